// Round 8
// baseline (224.606 us; speedup 1.0000x reference)
//
#include <hip/hip_runtime.h>
#include <math.h>

#define VOX 262144  // 64^3

__device__ __forceinline__ int clampi(int v, int lo, int hi) {
    return v < lo ? lo : (v > hi ? hi : v);
}

// ---- tiny prep: weight transpose w[c][ci][k] -> wT[k][ci][c]  +  stats zero ----
__global__ void k_wt_init(const float* __restrict__ w, float* __restrict__ wT,
                          float* __restrict__ stats) {
    int i = blockIdx.x * 256 + threadIdx.x;  // over 18*8*27 = 3888
    if (i < 3888) {
        int c = i / 216, r = i % 216;
        int ci = r / 27, k = r % 27;
        wT[(k * 8 + ci) * 18 + c] = w[i];
    }
    if (blockIdx.x == 0 && threadIdx.x < 44) stats[threadIdx.x] = 0.f;  // 36 bn + 8 gn
}

// ---- k_front: fused {feat transpose + offset conv (3x3x3, 8->18) + BN stats} ----
// Block = (fixed d, 4 wy rows, full 64-h row). Stages the 36 KB stencil tile once;
// ft transpose comes FREE from the tile's kd=1 rows. Conv consume bit-identical to
// R4's proven k_conv_off, weights from contiguous wT. (R7 version, unchanged.)
__global__ __launch_bounds__(256) void k_front(
        const float* __restrict__ f, const float* __restrict__ wT,
        const float* __restrict__ offb, float* __restrict__ ft,
        float* __restrict__ offs, float* __restrict__ stats) {
    __shared__ float tile[8 * 3 * 6 * 64];  // [ci][kd][wl][h], 36 KB
    int tid = threadIdx.x;
    int blk = blockIdx.x;
    int d = blk >> 4;                 // block's (uniform) d
    int wy0 = (blk & 15) << 2;        // base wy of its 4 rows

#pragma unroll
    for (int j = 0; j < 9; j++) {
        int flat = j * 256 + tid;           // 0..2303
        int row = flat >> 4;                // 0..143 = ci*18 + kd*6 + wl
        int off = (flat & 15) << 2;         // 0..60
        int ci = row / 18, rem = row % 18;
        int kd = rem / 6, wl = rem % 6;
        int dd = clampi(d + kd - 1, 0, 63);
        int ww = clampi(wy0 + wl - 1, 0, 63);
        *(float4*)(tile + row * 64 + off) =
            *(const float4*)(f + ci * VOX + (dd * 64 + ww) * 64 + off);
    }
    __syncthreads();

    int h = tid & 63, wl0 = tid >> 6;   // local wy row 0..3 (wave-uniform)
    int wy = wy0 + wl0;
    int idx = blk * 256 + tid;          // linear voxel: d*4096 + wy*64 + h

    // ft transpose from the tile (kd=1 -> dd=d, wl=wl0+1 -> ww=wy): free
    {
        float v[8];
#pragma unroll
        for (int ci = 0; ci < 8; ci++) v[ci] = tile[(ci * 18 + 6 + wl0 + 1) * 64 + h];
        float4* dst = (float4*)(ft + (size_t)idx * 8);  // coalesced 32B/thread
        dst[0] = make_float4(v[0], v[1], v[2], v[3]);
        dst[1] = make_float4(v[4], v[5], v[6], v[7]);
    }

    int hc0 = h > 0 ? h - 1 : 0;
    int hc2 = h < 63 ? h + 1 : 63;
    float mh0 = h > 0 ? 1.f : 0.f;
    float mh2 = h < 63 ? 1.f : 0.f;

    float acc[18];
#pragma unroll
    for (int c = 0; c < 18; c++) acc[c] = offb[c];

#pragma unroll
    for (int s = 0; s < 9; s++) {
        int kd = s / 3, kw = s % 3;
        int dd = d + kd - 1, ww = wy + kw - 1;
        bool ok = ((unsigned)dd < 64u) & ((unsigned)ww < 64u);  // wave-uniform
        if (ok) {
            const float* wrow = wT + s * 432;  // compile-time per unrolled s
#pragma unroll
            for (int ci = 0; ci < 8; ci++) {
                const float* lp = tile + (ci * 18 + kd * 6 + wl0 + kw) * 64;
                float v0 = lp[hc0] * mh0;
                float v1 = lp[h];
                float v2 = lp[hc2] * mh2;
                const float* wp = wrow + ci * 18;  // contiguous 18 floats per kh row
#pragma unroll
                for (int c = 0; c < 18; c++) {
                    float a = acc[c];
                    a = fmaf(v0, wp[c], a);
                    a = fmaf(v1, wp[144 + c], a);
                    a = fmaf(v2, wp[288 + c], a);
                    acc[c] = a;
                }
            }
        }
    }

#pragma unroll
    for (int c = 0; c < 18; c++) offs[c * VOX + idx] = acc[c];

    __shared__ float ls[36];
    if (tid < 36) ls[tid] = 0.f;
    __syncthreads();
#pragma unroll
    for (int c = 0; c < 18; c++) {
        float s = acc[c], q = acc[c] * acc[c];
#pragma unroll
        for (int o = 32; o > 0; o >>= 1) {
            s += __shfl_xor(s, o);
            q += __shfl_xor(q, o);
        }
        if ((tid & 63) == 0) {
            atomicAdd(&ls[c], s);
            atomicAdd(&ls[18 + c], q);
        }
    }
    __syncthreads();
    if (tid < 36) atomicAdd(&stats[tid], ls[tid]);
}

// ---- main: BN affine + tanh + cumsum + bilinear gather + (1,1,9) conv + GN stats.
//      2 threads per voxel (wave-aligned halves): half0 = taps 0-4 (+bias), half1 =
//      taps 5-8; each needs only 10 of 18 BN channels. Numerically verified in R2
//      (absmax 0.03125). UNCAPPED register budget this time (plain launch_bounds):
//      per-thread gather chain halves AND grid doubles -> up to 32 waves/CU. ----
#define TAP(K, ZA, YA)                                                              \
    {                                                                               \
        int xi = h + (K) - 4;                                                       \
        if (xi >= 0 && xi <= 62) {                                                  \
            float z = (float)d + (ZA);                                              \
            float y = (float)wy + (YA);                                             \
            float fz = floorf(z), fy = floorf(y);                                   \
            int iz = (int)fz, iy = (int)fy;                                         \
            int z0 = clampi(iz, 0, 63), z1 = clampi(iz + 1, 0, 63);                 \
            int y0 = clampi(iy, 0, 63), y1 = clampi(iy + 1, 0, 63);                 \
            float wz0 = (float)z1 - z, wz1 = z - (float)z0;                         \
            float wgy0 = (float)y1 - y, wgy1 = y - (float)y0;                       \
            float w00 = wz0 * wgy0, w01 = wz0 * wgy1;                               \
            float w10 = wz1 * wgy0, w11 = wz1 * wgy1;                               \
            const float4* p00 = (const float4*)(ft + (((z0 * 64 + y0) * 64 + xi) << 3)); \
            const float4* p01 = (const float4*)(ft + (((z0 * 64 + y1) * 64 + xi) << 3)); \
            const float4* p10 = (const float4*)(ft + (((z1 * 64 + y0) * 64 + xi) << 3)); \
            const float4* p11 = (const float4*)(ft + (((z1 * 64 + y1) * 64 + xi) << 3)); \
            float4 a00 = p00[0], b00 = p00[1];                                      \
            float4 a01 = p01[0], b01 = p01[1];                                      \
            float4 a10 = p10[0], b10 = p10[1];                                      \
            float4 a11 = p11[0], b11 = p11[1];                                      \
            float v[8];                                                             \
            v[0] = w00 * a00.x + w01 * a01.x + w10 * a10.x + w11 * a11.x;           \
            v[1] = w00 * a00.y + w01 * a01.y + w10 * a10.y + w11 * a11.y;           \
            v[2] = w00 * a00.z + w01 * a01.z + w10 * a10.z + w11 * a11.z;           \
            v[3] = w00 * a00.w + w01 * a01.w + w10 * a10.w + w11 * a11.w;           \
            v[4] = w00 * b00.x + w01 * b01.x + w10 * b10.x + w11 * b11.x;           \
            v[5] = w00 * b00.y + w01 * b01.y + w10 * b10.y + w11 * b11.y;           \
            v[6] = w00 * b00.z + w01 * b01.z + w10 * b10.z + w11 * b11.z;           \
            v[7] = w00 * b00.w + w01 * b01.w + w10 * b10.w + w11 * b11.w;           \
            _Pragma("unroll")                                                       \
            for (int ci = 0; ci < 8; ci++) {                                        \
                _Pragma("unroll")                                                   \
                for (int co = 0; co < 16; co++)                                     \
                    acc[co] = fmaf(v[ci], dw[(co * 8 + ci) * 9 + (K)], acc[co]);    \
            }                                                                       \
        }                                                                           \
    }

__global__ __launch_bounds__(256) void k_main(
        const float* __restrict__ ft, const float* __restrict__ offs,
        const float* __restrict__ stats, const float* __restrict__ bn_g,
        const float* __restrict__ bn_b, const float* __restrict__ dw,
        const float* __restrict__ db, float* __restrict__ out,
        float* __restrict__ gstats) {
    int t = threadIdx.x;
    const int half = __builtin_amdgcn_readfirstlane(t >> 7);  // wave-aligned, scalar
    int li = t & 127;
    int idx = blockIdx.x * 128 + li;
    int h = idx & 63, wy = (idx >> 6) & 63, d = idx >> 12;
    const float inv = 1.f / (float)VOX;

    // BN + tanh for this half's 10 channels: z ch cz0..cz0+4, y ch cz0+9..cz0+13
    const int cz0 = half * 4;  // SGPR -> stats/bn loads stay scalar
    float zt[5], yt[5];
#pragma unroll
    for (int j = 0; j < 5; j++) {
        int cz = cz0 + j, cy = cz + 9;
        float mz = stats[cz] * inv;
        float vz = stats[18 + cz] * inv - mz * mz;
        float rz = rsqrtf(vz + 1e-5f);
        zt[j] = tanhf(bn_g[cz] * ((offs[cz * VOX + idx] - mz) * rz) + bn_b[cz]);
        float my = stats[cy] * inv;
        float vy = stats[18 + cy] * inv - my * my;
        float ry = rsqrtf(vy + 1e-5f);
        yt[j] = tanhf(bn_g[cy] * ((offs[cy * VOX + idx] - my) * ry) + bn_b[cy]);
    }

    // center-out cumsum, only this half's taps (verified in R2)
    float za[5], ya[5];
    if (half == 0) {  // zt[j] = zo[j]; taps 0..4
        za[4] = zt[4];          ya[4] = yt[4];
        za[3] = za[4] + zt[3];  ya[3] = ya[4] + yt[3];
        za[2] = za[3] + zt[2];  ya[2] = ya[3] + yt[2];
        za[1] = za[2] + zt[1];  ya[1] = ya[2] + yt[1];
        za[0] = za[1] + zt[0];  ya[0] = ya[1] + yt[0];
    } else {          // zt[j] = zo[4+j]; taps 5..8 (za[j] <-> tap 5+j)
        za[0] = zt[0] + zt[1];  ya[0] = yt[0] + yt[1];
        za[1] = za[0] + zt[2];  ya[1] = ya[0] + yt[2];
        za[2] = za[1] + zt[3];  ya[2] = ya[1] + yt[3];
        za[3] = za[2] + zt[4];  ya[3] = ya[2] + yt[4];
    }

    float acc[16];
    if (half == 0) {
#pragma unroll
        for (int co = 0; co < 16; co++) acc[co] = db[co];
    } else {
#pragma unroll
        for (int co = 0; co < 16; co++) acc[co] = 0.f;
    }

    if (half == 0) {
        TAP(0, za[0], ya[0])
        TAP(1, za[1], ya[1])
        TAP(2, za[2], ya[2])
        TAP(3, za[3], ya[3])
        TAP(4, za[4], ya[4])
    } else {
        TAP(5, za[0], ya[0])
        TAP(6, za[1], ya[1])
        TAP(7, za[2], ya[2])
        TAP(8, za[3], ya[3])
    }

    __shared__ float red[128][17];  // +1 pad -> conflict-free merge
    __shared__ float ls[8];
    if (half) {
#pragma unroll
        for (int co = 0; co < 16; co++) red[li][co] = acc[co];
    }
    if (t < 8) ls[t] = 0.f;
    __syncthreads();
    if (half == 0) {
#pragma unroll
        for (int co = 0; co < 16; co++) acc[co] += red[li][co];
#pragma unroll
        for (int co = 0; co < 16; co++) out[co * VOX + idx] = acc[co];
        // group-norm stats: 4 groups of 4 channels (waves 0-1 only, full waves)
#pragma unroll
        for (int g = 0; g < 4; g++) {
            float s = acc[4 * g] + acc[4 * g + 1] + acc[4 * g + 2] + acc[4 * g + 3];
            float q = acc[4 * g] * acc[4 * g] + acc[4 * g + 1] * acc[4 * g + 1]
                    + acc[4 * g + 2] * acc[4 * g + 2] + acc[4 * g + 3] * acc[4 * g + 3];
#pragma unroll
            for (int o = 32; o > 0; o >>= 1) {
                s += __shfl_xor(s, o);
                q += __shfl_xor(q, o);
            }
            if ((t & 63) == 0) {
                atomicAdd(&ls[g], s);
                atomicAdd(&ls[4 + g], q);
            }
        }
    }
    __syncthreads();
    if (t < 8) atomicAdd(&gstats[t], ls[t]);
}

// ---- apply GroupNorm + ReLU in place on d_out (float4) ----
__global__ void k_gn(const float* __restrict__ gstats, const float* __restrict__ gn_g,
                     const float* __restrict__ gn_b, float* __restrict__ out) {
    int i = blockIdx.x * 256 + threadIdx.x;  // over 16*VOX/4 float4s
    int c = i >> 16;                         // (i*4)/VOX
    int g = c >> 2;
    const float invn = 1.f / (4.f * (float)VOX);
    float m = gstats[g] * invn;
    float var = gstats[4 + g] * invn - m * m;
    float rs = rsqrtf(var + 1e-5f);
    float gg = gn_g[c], gb = gn_b[c];
    float4 v = ((float4*)out)[i];
    v.x = (v.x - m) * rs * gg + gb; v.x = v.x > 0.f ? v.x : 0.f;
    v.y = (v.y - m) * rs * gg + gb; v.y = v.y > 0.f ? v.y : 0.f;
    v.z = (v.z - m) * rs * gg + gb; v.z = v.z > 0.f ? v.z : 0.f;
    v.w = (v.w - m) * rs * gg + gb; v.w = v.w > 0.f ? v.w : 0.f;
    ((float4*)out)[i] = v;
}

extern "C" void kernel_launch(void* const* d_in, const int* in_sizes, int n_in,
                              void* d_out, int out_size, void* d_ws, size_t ws_size,
                              hipStream_t stream) {
    const float* f    = (const float*)d_in[0];
    const float* offw = (const float*)d_in[1];
    const float* offb = (const float*)d_in[2];
    const float* bng  = (const float*)d_in[3];
    const float* bnb  = (const float*)d_in[4];
    const float* dcnw = (const float*)d_in[5];
    const float* dcnb = (const float*)d_in[6];
    const float* gng  = (const float*)d_in[7];
    const float* gnb  = (const float*)d_in[8];
    float* out = (float*)d_out;

    float* ws     = (float*)d_ws;
    float* ft     = ws;               // 8*VOX floats (featT)
    float* offs   = ws + 8 * VOX;     // 18*VOX floats (raw offset conv)
    float* stats  = offs + 18 * VOX;  // 36 bn stats + 8 gn stats (contiguous)
    // wT lives in d_out's first 3888 floats: dead until k_main overwrites out.
    float* wT = out;

    hipLaunchKernelGGL(k_wt_init, dim3(16), dim3(256), 0, stream, offw, wT, stats);
    hipLaunchKernelGGL(k_front, dim3(VOX / 256), dim3(256), 0, stream,
                       f, wT, offb, ft, offs, stats);
    hipLaunchKernelGGL(k_main, dim3(VOX / 128), dim3(256), 0, stream,
                       ft, offs, stats, bng, bnb, dcnw, dcnb, out, stats + 36);
    hipLaunchKernelGGL(k_gn, dim3((16 * VOX / 4) / 256), dim3(256), 0, stream,
                       stats + 36, gng, gnb, out);
}

// Round 9
// 220.717 us; speedup vs baseline: 1.0176x; 1.0176x over previous
//
#include <hip/hip_runtime.h>
#include <math.h>

#define VOX 262144  // 64^3

__device__ __forceinline__ int clampi(int v, int lo, int hi) {
    return v < lo ? lo : (v > hi ? hi : v);
}

__device__ __forceinline__ float fast_tanh(float u) {
    // (e^2u - 1)/(e^2u + 1); clamp keeps e^2u finite (|u|>9 -> tanh==+-1).
    // Numerically validated in R1 (absmax identical to tanhf build: 0.03125).
    u = fminf(fmaxf(u, -9.f), 9.f);
    float e2 = __expf(2.f * u);
    return (e2 - 1.f) * __builtin_amdgcn_rcpf(e2 + 1.f);
}

// ---- tiny prep: weight transpose w[c][ci][k] -> wT[k][ci][c]  +  stats zero ----
__global__ void k_wt_init(const float* __restrict__ w, float* __restrict__ wT,
                          float* __restrict__ stats) {
    int i = blockIdx.x * 256 + threadIdx.x;  // over 18*8*27 = 3888
    if (i < 3888) {
        int c = i / 216, r = i % 216;
        int ci = r / 27, k = r % 27;
        wT[(k * 8 + ci) * 18 + c] = w[i];
    }
    if (blockIdx.x == 0 && threadIdx.x < 44) stats[threadIdx.x] = 0.f;  // 36 bn + 8 gn
}

// ---- k_front: fused {feat transpose + offset conv (3x3x3, 8->18) + BN stats} ----
// Block = (fixed d, 4 wy rows, full 64-h row); 36 KB tile staged once; ft transpose
// free from the tile's kd=1 rows (R6/R7-proven). NEW vs R7: per s-step, all 24
// ds_reads (8 ci x {h-1,h,h+1}) are hoisted as NAMED scalars before the 432-FMA
// wall, so their latency overlaps instead of stalling every 3 loads. Consumption
// order unchanged -> bit-identical FP result.
#define LD(CI)                                                        \
    float r##CI##a = base[(CI)*1152 + hc0];                           \
    float r##CI##b = base[(CI)*1152 + h];                             \
    float r##CI##c = base[(CI)*1152 + hc2];

#define USE(CI)                                                       \
    {                                                                 \
        float v0 = r##CI##a * mh0;                                    \
        float v1 = r##CI##b;                                          \
        float v2 = r##CI##c * mh2;                                    \
        const float* wp = wrow + (CI) * 18;                           \
        _Pragma("unroll")                                             \
        for (int c = 0; c < 18; c++) {                                \
            float a = acc[c];                                         \
            a = fmaf(v0, wp[c], a);                                   \
            a = fmaf(v1, wp[144 + c], a);                             \
            a = fmaf(v2, wp[288 + c], a);                             \
            acc[c] = a;                                               \
        }                                                             \
    }

__global__ __launch_bounds__(256) void k_front(
        const float* __restrict__ f, const float* __restrict__ wT,
        const float* __restrict__ offb, float* __restrict__ ft,
        float* __restrict__ offs, float* __restrict__ stats) {
    __shared__ float tile[8 * 3 * 6 * 64];  // [ci][kd][wl][h], 36 KB
    int tid = threadIdx.x;
    int blk = blockIdx.x;
    int d = blk >> 4;                 // block's (uniform) d
    int wy0 = (blk & 15) << 2;        // base wy of its 4 rows

    // ---- stage 36 KB: 2304 float4, 9 per thread, coalesced ----
#pragma unroll
    for (int j = 0; j < 9; j++) {
        int flat = j * 256 + tid;           // 0..2303
        int row = flat >> 4;                // 0..143 = ci*18 + kd*6 + wl
        int off = (flat & 15) << 2;         // 0..60
        int ci = row / 18, rem = row % 18;
        int kd = rem / 6, wl = rem % 6;
        int dd = clampi(d + kd - 1, 0, 63);
        int ww = clampi(wy0 + wl - 1, 0, 63);
        *(float4*)(tile + row * 64 + off) =
            *(const float4*)(f + ci * VOX + (dd * 64 + ww) * 64 + off);
    }
    __syncthreads();

    int h = tid & 63, wl0 = tid >> 6;   // local wy row 0..3 (wave-uniform)
    int wy = wy0 + wl0;
    int idx = blk * 256 + tid;          // linear voxel: d*4096 + wy*64 + h

    // ---- ft transpose from the tile (kd=1 -> dd=d, wl=wl0+1 -> ww=wy): free ----
    {
        float v[8];
#pragma unroll
        for (int ci = 0; ci < 8; ci++) v[ci] = tile[(ci * 18 + 6 + wl0 + 1) * 64 + h];
        float4* dst = (float4*)(ft + (size_t)idx * 8);  // coalesced 32B/thread
        dst[0] = make_float4(v[0], v[1], v[2], v[3]);
        dst[1] = make_float4(v[4], v[5], v[6], v[7]);
    }

    int hc0 = h > 0 ? h - 1 : 0;
    int hc2 = h < 63 ? h + 1 : 63;
    float mh0 = h > 0 ? 1.f : 0.f;
    float mh2 = h < 63 ? 1.f : 0.f;

    float acc[18];
#pragma unroll
    for (int c = 0; c < 18; c++) acc[c] = offb[c];

#pragma unroll
    for (int s = 0; s < 9; s++) {
        int kd = s / 3, kw = s % 3;
        int dd = d + kd - 1, ww = wy + kw - 1;
        bool ok = ((unsigned)dd < 64u) & ((unsigned)ww < 64u);  // wave-uniform
        if (ok) {
            const float* wrow = wT + s * 432;                   // compile-time per s
            const float* base = tile + (kd * 6 + wl0 + kw) * 64;  // + ci*1152
            // batch: issue all 24 ds_reads, then consume (same FP order as R7)
            LD(0) LD(1) LD(2) LD(3) LD(4) LD(5) LD(6) LD(7)
            USE(0) USE(1) USE(2) USE(3) USE(4) USE(5) USE(6) USE(7)
        }
    }

#pragma unroll
    for (int c = 0; c < 18; c++) offs[c * VOX + idx] = acc[c];

    __shared__ float ls[36];
    if (tid < 36) ls[tid] = 0.f;
    __syncthreads();
#pragma unroll
    for (int c = 0; c < 18; c++) {
        float s = acc[c], q = acc[c] * acc[c];
#pragma unroll
        for (int o = 32; o > 0; o >>= 1) {
            s += __shfl_xor(s, o);
            q += __shfl_xor(q, o);
        }
        if ((tid & 63) == 0) {
            atomicAdd(&ls[c], s);
            atomicAdd(&ls[18 + c], q);
        }
    }
    __syncthreads();
    if (tid < 36) atomicAdd(&stats[tid], ls[tid]);
}

// ---- main: BN affine + fast_tanh + center-out cumsum + bilinear(z,y) gather +
//      (1,1,9) conv + GroupNorm stats. Structure = proven 58.5 us R0/R4 body;
//      ONLY change: tanhf -> fast_tanh (R1-validated numerics). ----
__global__ __launch_bounds__(256) void k_main(
        const float* __restrict__ ft, const float* __restrict__ offs,
        const float* __restrict__ stats, const float* __restrict__ bn_g,
        const float* __restrict__ bn_b, const float* __restrict__ dw,
        const float* __restrict__ db, float* __restrict__ out,
        float* __restrict__ gstats) {
    int idx = blockIdx.x * 256 + threadIdx.x;
    int h = idx & 63, wy = (idx >> 6) & 63, d = idx >> 12;
    const float inv = 1.f / (float)VOX;

    float zo[9], yo[9];
#pragma unroll
    for (int c = 0; c < 18; c++) {
        float m = stats[c] * inv;
        float var = stats[18 + c] * inv - m * m;
        float rs = rsqrtf(var + 1e-5f);
        float t = fast_tanh(bn_g[c] * ((offs[c * VOX + idx] - m) * rs) + bn_b[c]);
        if (c < 9) zo[c] = t; else yo[c - 9] = t;
    }

    // cumsum outward from center (K=9, CENTER=4)
    float za[9], ya[9];
    za[4] = zo[4]; ya[4] = yo[4];
#pragma unroll
    for (int k = 5; k < 9; k++) { za[k] = za[k - 1] + zo[k]; ya[k] = ya[k - 1] + yo[k]; }
#pragma unroll
    for (int k = 3; k >= 0; k--) { za[k] = za[k + 1] + zo[k]; ya[k] = ya[k + 1] + yo[k]; }

    float acc[16];
#pragma unroll
    for (int co = 0; co < 16; co++) acc[co] = db[co];

#pragma unroll
    for (int k = 0; k < 9; k++) {
        int xi = h + k - 4;
        // x is exactly integer: weight 1 for xi in [0,62], exactly 0 otherwise
        // (incl. xi==63 where both clipped x-weights vanish).
        if (xi >= 0 && xi <= 62) {
            float z = (float)d + za[k];
            float y = (float)wy + ya[k];
            float fz = floorf(z), fy = floorf(y);
            int iz = (int)fz, iy = (int)fy;
            int z0 = clampi(iz, 0, 63), z1 = clampi(iz + 1, 0, 63);
            int y0 = clampi(iy, 0, 63), y1 = clampi(iy + 1, 0, 63);
            float wz0 = (float)z1 - z, wz1 = z - (float)z0;
            float wy0 = (float)y1 - y, wy1 = y - (float)y0;
            float w00 = wz0 * wy0, w01 = wz0 * wy1, w10 = wz1 * wy0, w11 = wz1 * wy1;

            const float4* p00 = (const float4*)(ft + (((z0 * 64 + y0) * 64 + xi) << 3));
            const float4* p01 = (const float4*)(ft + (((z0 * 64 + y1) * 64 + xi) << 3));
            const float4* p10 = (const float4*)(ft + (((z1 * 64 + y0) * 64 + xi) << 3));
            const float4* p11 = (const float4*)(ft + (((z1 * 64 + y1) * 64 + xi) << 3));
            float4 a00 = p00[0], b00 = p00[1];
            float4 a01 = p01[0], b01 = p01[1];
            float4 a10 = p10[0], b10 = p10[1];
            float4 a11 = p11[0], b11 = p11[1];

            float v[8];
            v[0] = w00 * a00.x + w01 * a01.x + w10 * a10.x + w11 * a11.x;
            v[1] = w00 * a00.y + w01 * a01.y + w10 * a10.y + w11 * a11.y;
            v[2] = w00 * a00.z + w01 * a01.z + w10 * a10.z + w11 * a11.z;
            v[3] = w00 * a00.w + w01 * a01.w + w10 * a10.w + w11 * a11.w;
            v[4] = w00 * b00.x + w01 * b01.x + w10 * b10.x + w11 * b11.x;
            v[5] = w00 * b00.y + w01 * b01.y + w10 * b10.y + w11 * b11.y;
            v[6] = w00 * b00.z + w01 * b01.z + w10 * b10.z + w11 * b11.z;
            v[7] = w00 * b00.w + w01 * b01.w + w10 * b10.w + w11 * b11.w;

#pragma unroll
            for (int ci = 0; ci < 8; ci++) {
#pragma unroll
                for (int co = 0; co < 16; co++)
                    acc[co] = fmaf(v[ci], dw[(co * 8 + ci) * 9 + k], acc[co]);
            }
        }
    }

#pragma unroll
    for (int co = 0; co < 16; co++) out[co * VOX + idx] = acc[co];

    // group-norm stats: 4 groups of 4 channels
    __shared__ float ls[8];
    if (threadIdx.x < 8) ls[threadIdx.x] = 0.f;
    __syncthreads();
#pragma unroll
    for (int g = 0; g < 4; g++) {
        float s = acc[4 * g] + acc[4 * g + 1] + acc[4 * g + 2] + acc[4 * g + 3];
        float q = acc[4 * g] * acc[4 * g] + acc[4 * g + 1] * acc[4 * g + 1]
                + acc[4 * g + 2] * acc[4 * g + 2] + acc[4 * g + 3] * acc[4 * g + 3];
#pragma unroll
        for (int o = 32; o > 0; o >>= 1) {
            s += __shfl_xor(s, o);
            q += __shfl_xor(q, o);
        }
        if ((threadIdx.x & 63) == 0) {
            atomicAdd(&ls[g], s);
            atomicAdd(&ls[4 + g], q);
        }
    }
    __syncthreads();
    if (threadIdx.x < 8) atomicAdd(&gstats[threadIdx.x], ls[threadIdx.x]);
}

// ---- apply GroupNorm + ReLU in place on d_out (float4) ----
__global__ void k_gn(const float* __restrict__ gstats, const float* __restrict__ gn_g,
                     const float* __restrict__ gn_b, float* __restrict__ out) {
    int i = blockIdx.x * 256 + threadIdx.x;  // over 16*VOX/4 float4s
    int c = i >> 16;                         // (i*4)/VOX
    int g = c >> 2;
    const float invn = 1.f / (4.f * (float)VOX);
    float m = gstats[g] * invn;
    float var = gstats[4 + g] * invn - m * m;
    float rs = rsqrtf(var + 1e-5f);
    float gg = gn_g[c], gb = gn_b[c];
    float4 v = ((float4*)out)[i];
    v.x = (v.x - m) * rs * gg + gb; v.x = v.x > 0.f ? v.x : 0.f;
    v.y = (v.y - m) * rs * gg + gb; v.y = v.y > 0.f ? v.y : 0.f;
    v.z = (v.z - m) * rs * gg + gb; v.z = v.z > 0.f ? v.z : 0.f;
    v.w = (v.w - m) * rs * gg + gb; v.w = v.w > 0.f ? v.w : 0.f;
    ((float4*)out)[i] = v;
}

extern "C" void kernel_launch(void* const* d_in, const int* in_sizes, int n_in,
                              void* d_out, int out_size, void* d_ws, size_t ws_size,
                              hipStream_t stream) {
    const float* f    = (const float*)d_in[0];
    const float* offw = (const float*)d_in[1];
    const float* offb = (const float*)d_in[2];
    const float* bng  = (const float*)d_in[3];
    const float* bnb  = (const float*)d_in[4];
    const float* dcnw = (const float*)d_in[5];
    const float* dcnb = (const float*)d_in[6];
    const float* gng  = (const float*)d_in[7];
    const float* gnb  = (const float*)d_in[8];
    float* out = (float*)d_out;

    float* ws     = (float*)d_ws;
    float* ft     = ws;               // 8*VOX floats (featT)
    float* offs   = ws + 8 * VOX;     // 18*VOX floats (raw offset conv)
    float* stats  = offs + 18 * VOX;  // 36 bn stats + 8 gn stats (contiguous)
    // wT lives in d_out's first 3888 floats: dead until k_main overwrites out.
    float* wT = out;

    hipLaunchKernelGGL(k_wt_init, dim3(16), dim3(256), 0, stream, offw, wT, stats);
    hipLaunchKernelGGL(k_front, dim3(VOX / 256), dim3(256), 0, stream,
                       f, wT, offb, ft, offs, stats);
    hipLaunchKernelGGL(k_main, dim3(VOX / 256), dim3(256), 0, stream,
                       ft, offs, stats, bng, bnb, dcnw, dcnb, out, stats + 36);
    hipLaunchKernelGGL(k_gn, dim3((16 * VOX / 4) / 256), dim3(256), 0, stream,
                       stats + 36, gng, gnb, out);
}

// Round 11
// 184.910 us; speedup vs baseline: 1.2147x; 1.1936x over previous
//
#include <hip/hip_runtime.h>
#include <math.h>

#define VOX 262144  // 64^3

__device__ __forceinline__ int clampi(int v, int lo, int hi) {
    return v < lo ? lo : (v > hi ? hi : v);
}

__device__ __forceinline__ float fast_tanh(float u) {
    // (e^2u - 1)/(e^2u + 1); clamp keeps e^2u finite (|u|>9 -> tanh==+-1).
    // Validated: R1/R9 builds with this in k_main pass at absmax 0.03125,
    // identical to all tanhf builds.
    u = fminf(fmaxf(u, -9.f), 9.f);
    float e2 = __expf(2.f * u);
    return (e2 - 1.f) * __builtin_amdgcn_rcpf(e2 + 1.f);
}

// ---- fused prep: feat transpose (coalesced both sides) + stats zero + weight transpose ----
__global__ void k_pre(const float* __restrict__ f, float* __restrict__ ft,
                      const float* __restrict__ w, float* __restrict__ wT,
                      float* __restrict__ stats) {
    int vox = blockIdx.x * 256 + threadIdx.x;
    float v[8];
#pragma unroll
    for (int ci = 0; ci < 8; ci++) v[ci] = f[ci * VOX + vox];  // 8 coalesced reads
    float4* dst = (float4*)(ft + (size_t)vox * 8);             // coalesced 32B/thread writes
    dst[0] = make_float4(v[0], v[1], v[2], v[3]);
    dst[1] = make_float4(v[4], v[5], v[6], v[7]);

    if (blockIdx.x == 0) {
        if (threadIdx.x < 64) stats[threadIdx.x] = 0.f;  // 36 bn + 8 gn stats
    } else if (blockIdx.x == 1) {
        for (int i = threadIdx.x; i < 3888; i += 256) {  // w[c][ci][k] -> wT[k][ci][c]
            int c = i / 216, r = i % 216;
            int ci = r / 27, k = r % 27;
            wT[(k * 8 + ci) * 18 + c] = w[i];
        }
    }
}

// ---- offset conv (3x3x3, 8 -> 18 ch) + BN sum/sumsq reduction ----
// LDS-staged (R4-proven, 188.5 us config): block = (fixed d, 4 wy rows, full h-row).
// Stencil footprint staged once with coalesced float4 loads; the 216 stencil reads
// per thread are ds_read_b32 in small 3-load batches (compiler-scheduled — R9 proved
// manual 24-load batching regresses).
__global__ __launch_bounds__(256) void k_conv_off(
        const float* __restrict__ f, const float* __restrict__ wT,
        const float* __restrict__ b, float* __restrict__ offs,
        float* __restrict__ stats) {
    __shared__ float tile[8 * 3 * 6 * 64];  // [ci][kd][wl][h], 36 KB
    int tid = threadIdx.x;
    int blk = blockIdx.x;
    int d = blk >> 4;                 // block's (uniform) d
    int wy0 = (blk & 15) << 2;        // base wy of its 4 rows

    // ---- stage 36 KB: 2304 float4, 9 per thread, coalesced ----
#pragma unroll
    for (int j = 0; j < 9; j++) {
        int flat = j * 256 + tid;           // 0..2303
        int row = flat >> 4;                // 0..143 = ci*18 + kd*6 + wl
        int off = (flat & 15) << 2;         // 0..60
        int ci = row / 18, rem = row % 18;
        int kd = rem / 6, wl = rem % 6;
        int dd = clampi(d + kd - 1, 0, 63);
        int ww = clampi(wy0 + wl - 1, 0, 63);
        *(float4*)(tile + row * 64 + off) =
            *(const float4*)(f + ci * VOX + (dd * 64 + ww) * 64 + off);
    }
    __syncthreads();

    int h = tid & 63, wl0 = tid >> 6;   // local wy row 0..3 (wave-uniform)
    int wy = wy0 + wl0;
    int idx = blk * 256 + tid;          // same output mapping as before

    int hc0 = h > 0 ? h - 1 : 0;
    int hc2 = h < 63 ? h + 1 : 63;
    float mh0 = h > 0 ? 1.f : 0.f;
    float mh2 = h < 63 ? 1.f : 0.f;

    float acc[18];
#pragma unroll
    for (int c = 0; c < 18; c++) acc[c] = b[c];

#pragma unroll
    for (int s = 0; s < 9; s++) {
        int kd = s / 3, kw = s % 3;
        int dd = d + kd - 1, ww = wy + kw - 1;
        bool ok = ((unsigned)dd < 64u) & ((unsigned)ww < 64u);  // wave-uniform
        if (ok) {
            const float* wrow = wT + s * 432;  // compile-time offset per unrolled s
#pragma unroll
            for (int ci = 0; ci < 8; ci++) {
                const float* lp = tile + (ci * 18 + kd * 6 + wl0 + kw) * 64;
                float v0 = lp[hc0] * mh0;
                float v1 = lp[h];
                float v2 = lp[hc2] * mh2;
                const float* wp = wrow + ci * 18;
#pragma unroll
                for (int c = 0; c < 18; c++) {
                    float a = acc[c];
                    a = fmaf(v0, wp[c], a);
                    a = fmaf(v1, wp[144 + c], a);
                    a = fmaf(v2, wp[288 + c], a);
                    acc[c] = a;
                }
            }
        }
    }

#pragma unroll
    for (int c = 0; c < 18; c++) offs[c * VOX + idx] = acc[c];

    __shared__ float ls[36];
    if (tid < 36) ls[tid] = 0.f;
    __syncthreads();
#pragma unroll
    for (int c = 0; c < 18; c++) {
        float s = acc[c], q = acc[c] * acc[c];
#pragma unroll
        for (int o = 32; o > 0; o >>= 1) {
            s += __shfl_xor(s, o);
            q += __shfl_xor(q, o);
        }
        if ((tid & 63) == 0) {
            atomicAdd(&ls[c], s);
            atomicAdd(&ls[18 + c], q);
        }
    }
    __syncthreads();
    if (tid < 36) atomicAdd(&stats[tid], ls[tid]);
}

// ---- main: BN affine + fast_tanh + center-out cumsum + bilinear(z,y) gather +
//      (1,1,9) conv + GroupNorm stats. Proven 58.5 us R0/R4 body; the ONLY delta
//      is tanhf -> fast_tanh (isolated change, carried from the aborted R10). ----
__global__ __launch_bounds__(256) void k_main(
        const float* __restrict__ ft, const float* __restrict__ offs,
        const float* __restrict__ stats, const float* __restrict__ bn_g,
        const float* __restrict__ bn_b, const float* __restrict__ dw,
        const float* __restrict__ db, float* __restrict__ out,
        float* __restrict__ gstats) {
    int idx = blockIdx.x * 256 + threadIdx.x;
    int h = idx & 63, wy = (idx >> 6) & 63, d = idx >> 12;
    const float inv = 1.f / (float)VOX;

    float zo[9], yo[9];
#pragma unroll
    for (int c = 0; c < 18; c++) {
        float m = stats[c] * inv;
        float var = stats[18 + c] * inv - m * m;
        float rs = rsqrtf(var + 1e-5f);
        float t = fast_tanh(bn_g[c] * ((offs[c * VOX + idx] - m) * rs) + bn_b[c]);
        if (c < 9) zo[c] = t; else yo[c - 9] = t;
    }

    // cumsum outward from center (K=9, CENTER=4)
    float za[9], ya[9];
    za[4] = zo[4]; ya[4] = yo[4];
#pragma unroll
    for (int k = 5; k < 9; k++) { za[k] = za[k - 1] + zo[k]; ya[k] = ya[k - 1] + yo[k]; }
#pragma unroll
    for (int k = 3; k >= 0; k--) { za[k] = za[k + 1] + zo[k]; ya[k] = ya[k + 1] + yo[k]; }

    float acc[16];
#pragma unroll
    for (int co = 0; co < 16; co++) acc[co] = db[co];

#pragma unroll
    for (int k = 0; k < 9; k++) {
        int xi = h + k - 4;
        // x is exactly integer: weight 1 for xi in [0,62], exactly 0 otherwise
        // (incl. xi==63 where both clipped x-weights vanish).
        if (xi >= 0 && xi <= 62) {
            float z = (float)d + za[k];
            float y = (float)wy + ya[k];
            float fz = floorf(z), fy = floorf(y);
            int iz = (int)fz, iy = (int)fy;
            int z0 = clampi(iz, 0, 63), z1 = clampi(iz + 1, 0, 63);
            int y0 = clampi(iy, 0, 63), y1 = clampi(iy + 1, 0, 63);
            float wz0 = (float)z1 - z, wz1 = z - (float)z0;
            float wy0 = (float)y1 - y, wy1 = y - (float)y0;
            float w00 = wz0 * wy0, w01 = wz0 * wy1, w10 = wz1 * wy0, w11 = wz1 * wy1;

            const float4* p00 = (const float4*)(ft + (((z0 * 64 + y0) * 64 + xi) << 3));
            const float4* p01 = (const float4*)(ft + (((z0 * 64 + y1) * 64 + xi) << 3));
            const float4* p10 = (const float4*)(ft + (((z1 * 64 + y0) * 64 + xi) << 3));
            const float4* p11 = (const float4*)(ft + (((z1 * 64 + y1) * 64 + xi) << 3));
            float4 a00 = p00[0], b00 = p00[1];
            float4 a01 = p01[0], b01 = p01[1];
            float4 a10 = p10[0], b10 = p10[1];
            float4 a11 = p11[0], b11 = p11[1];

            float v[8];
            v[0] = w00 * a00.x + w01 * a01.x + w10 * a10.x + w11 * a11.x;
            v[1] = w00 * a00.y + w01 * a01.y + w10 * a10.y + w11 * a11.y;
            v[2] = w00 * a00.z + w01 * a01.z + w10 * a10.z + w11 * a11.z;
            v[3] = w00 * a00.w + w01 * a01.w + w10 * a10.w + w11 * a11.w;
            v[4] = w00 * b00.x + w01 * b01.x + w10 * b10.x + w11 * b11.x;
            v[5] = w00 * b00.y + w01 * b01.y + w10 * b10.y + w11 * b11.y;
            v[6] = w00 * b00.z + w01 * b01.z + w10 * b10.z + w11 * b11.z;
            v[7] = w00 * b00.w + w01 * b01.w + w10 * b10.w + w11 * b11.w;

#pragma unroll
            for (int ci = 0; ci < 8; ci++) {
#pragma unroll
                for (int co = 0; co < 16; co++)
                    acc[co] = fmaf(v[ci], dw[(co * 8 + ci) * 9 + k], acc[co]);
            }
        }
    }

#pragma unroll
    for (int co = 0; co < 16; co++) out[co * VOX + idx] = acc[co];

    // group-norm stats: 4 groups of 4 channels
    __shared__ float ls[8];
    if (threadIdx.x < 8) ls[threadIdx.x] = 0.f;
    __syncthreads();
#pragma unroll
    for (int g = 0; g < 4; g++) {
        float s = acc[4 * g] + acc[4 * g + 1] + acc[4 * g + 2] + acc[4 * g + 3];
        float q = acc[4 * g] * acc[4 * g] + acc[4 * g + 1] * acc[4 * g + 1]
                + acc[4 * g + 2] * acc[4 * g + 2] + acc[4 * g + 3] * acc[4 * g + 3];
#pragma unroll
        for (int o = 32; o > 0; o >>= 1) {
            s += __shfl_xor(s, o);
            q += __shfl_xor(q, o);
        }
        if ((threadIdx.x & 63) == 0) {
            atomicAdd(&ls[g], s);
            atomicAdd(&ls[4 + g], q);
        }
    }
    __syncthreads();
    if (threadIdx.x < 8) atomicAdd(&gstats[threadIdx.x], ls[threadIdx.x]);
}

// ---- apply GroupNorm + ReLU in place on d_out (float4) ----
__global__ void k_gn(const float* __restrict__ gstats, const float* __restrict__ gn_g,
                     const float* __restrict__ gn_b, float* __restrict__ out) {
    int i = blockIdx.x * 256 + threadIdx.x;  // over 16*VOX/4 float4s
    int c = i >> 16;                         // (i*4)/VOX
    int g = c >> 2;
    const float invn = 1.f / (4.f * (float)VOX);
    float m = gstats[g] * invn;
    float var = gstats[4 + g] * invn - m * m;
    float rs = rsqrtf(var + 1e-5f);
    float gg = gn_g[c], gb = gn_b[c];
    float4 v = ((float4*)out)[i];
    v.x = (v.x - m) * rs * gg + gb; v.x = v.x > 0.f ? v.x : 0.f;
    v.y = (v.y - m) * rs * gg + gb; v.y = v.y > 0.f ? v.y : 0.f;
    v.z = (v.z - m) * rs * gg + gb; v.z = v.z > 0.f ? v.z : 0.f;
    v.w = (v.w - m) * rs * gg + gb; v.w = v.w > 0.f ? v.w : 0.f;
    ((float4*)out)[i] = v;
}

extern "C" void kernel_launch(void* const* d_in, const int* in_sizes, int n_in,
                              void* d_out, int out_size, void* d_ws, size_t ws_size,
                              hipStream_t stream) {
    const float* f    = (const float*)d_in[0];
    const float* offw = (const float*)d_in[1];
    const float* offb = (const float*)d_in[2];
    const float* bng  = (const float*)d_in[3];
    const float* bnb  = (const float*)d_in[4];
    const float* dcnw = (const float*)d_in[5];
    const float* dcnb = (const float*)d_in[6];
    const float* gng  = (const float*)d_in[7];
    const float* gnb  = (const float*)d_in[8];
    float* out = (float*)d_out;

    float* ws     = (float*)d_ws;
    float* ft     = ws;               // 8*VOX floats (featT)
    float* offs   = ws + 8 * VOX;     // 18*VOX floats (raw offset conv)
    float* stats  = offs + 18 * VOX;  // 36 bn stats + 8 gn stats
    float* gstats = stats + 36;
    // wT lives in d_out's first 3888 floats: dead until k_main overwrites out.
    float* wT = out;

    hipLaunchKernelGGL(k_pre, dim3(VOX / 256), dim3(256), 0, stream, f, ft, offw, wT, stats);
    hipLaunchKernelGGL(k_conv_off, dim3(VOX / 256), dim3(256), 0, stream,
                       f, wT, offb, offs, stats);
    hipLaunchKernelGGL(k_main, dim3(VOX / 256), dim3(256), 0, stream,
                       ft, offs, stats, bng, bnb, dcnw, dcnb, out, gstats);
    hipLaunchKernelGGL(k_gn, dim3((16 * VOX / 4) / 256), dim3(256), 0, stream,
                       gstats, gng, gnb, out);
}

// Round 12
// 168.486 us; speedup vs baseline: 1.3331x; 1.0975x over previous
//
#include <hip/hip_runtime.h>
#include <hip/hip_fp16.h>
#include <math.h>

#define VOX 262144  // 64^3

__device__ __forceinline__ int clampi(int v, int lo, int hi) {
    return v < lo ? lo : (v > hi ? hi : v);
}

__device__ __forceinline__ float fast_tanh(float u) {
    // (e^2u - 1)/(e^2u + 1); clamp keeps e^2u finite (|u|>9 -> tanh==+-1).
    // Validated R1/R9/R11: absmax 0.03125, identical to tanhf builds.
    u = fminf(fmaxf(u, -9.f), 9.f);
    float e2 = __expf(2.f * u);
    return (e2 - 1.f) * __builtin_amdgcn_rcpf(e2 + 1.f);
}

// ---- fused prep: feat transpose -> fp16 [z][y][x][ci] (4 MB, fits one XCD L2)
//      + stats zero + weight transpose ----
__global__ void k_pre(const float* __restrict__ f, __half* __restrict__ fth,
                      const float* __restrict__ w, float* __restrict__ wT,
                      float* __restrict__ stats) {
    int vox = blockIdx.x * 256 + threadIdx.x;
    float v[8];
#pragma unroll
    for (int ci = 0; ci < 8; ci++) v[ci] = f[ci * VOX + vox];  // 8 coalesced reads
    __half2 p[4];
#pragma unroll
    for (int j = 0; j < 4; j++) p[j] = __floats2half2_rn(v[2 * j], v[2 * j + 1]);
    *(float4*)(fth + (size_t)vox * 8) = *(const float4*)p;  // coalesced 16B/thread

    if (blockIdx.x == 0) {
        if (threadIdx.x < 64) stats[threadIdx.x] = 0.f;  // 36 bn + 8 gn stats
    } else if (blockIdx.x == 1) {
        for (int i = threadIdx.x; i < 3888; i += 256) {  // w[c][ci][k] -> wT[k][ci][c]
            int c = i / 216, r = i % 216;
            int ci = r / 27, k = r % 27;
            wT[(k * 8 + ci) * 18 + c] = w[i];
        }
    }
}

// ---- offset conv (3x3x3, 8 -> 18 ch) + BN sum/sumsq reduction ----
// LDS-staged (R4/R11-proven): block = (fixed d, 4 wy rows, full h-row).
__global__ __launch_bounds__(256) void k_conv_off(
        const float* __restrict__ f, const float* __restrict__ wT,
        const float* __restrict__ b, float* __restrict__ offs,
        float* __restrict__ stats) {
    __shared__ float tile[8 * 3 * 6 * 64];  // [ci][kd][wl][h], 36 KB
    int tid = threadIdx.x;
    int blk = blockIdx.x;
    int d = blk >> 4;                 // block's (uniform) d
    int wy0 = (blk & 15) << 2;        // base wy of its 4 rows

    // ---- stage 36 KB: 2304 float4, 9 per thread, coalesced ----
#pragma unroll
    for (int j = 0; j < 9; j++) {
        int flat = j * 256 + tid;           // 0..2303
        int row = flat >> 4;                // 0..143 = ci*18 + kd*6 + wl
        int off = (flat & 15) << 2;         // 0..60
        int ci = row / 18, rem = row % 18;
        int kd = rem / 6, wl = rem % 6;
        int dd = clampi(d + kd - 1, 0, 63);
        int ww = clampi(wy0 + wl - 1, 0, 63);
        *(float4*)(tile + row * 64 + off) =
            *(const float4*)(f + ci * VOX + (dd * 64 + ww) * 64 + off);
    }
    __syncthreads();

    int h = tid & 63, wl0 = tid >> 6;   // local wy row 0..3 (wave-uniform)
    int wy = wy0 + wl0;
    int idx = blk * 256 + tid;          // same output mapping as before

    int hc0 = h > 0 ? h - 1 : 0;
    int hc2 = h < 63 ? h + 1 : 63;
    float mh0 = h > 0 ? 1.f : 0.f;
    float mh2 = h < 63 ? 1.f : 0.f;

    float acc[18];
#pragma unroll
    for (int c = 0; c < 18; c++) acc[c] = b[c];

#pragma unroll
    for (int s = 0; s < 9; s++) {
        int kd = s / 3, kw = s % 3;
        int dd = d + kd - 1, ww = wy + kw - 1;
        bool ok = ((unsigned)dd < 64u) & ((unsigned)ww < 64u);  // wave-uniform
        if (ok) {
            const float* wrow = wT + s * 432;  // compile-time offset per unrolled s
#pragma unroll
            for (int ci = 0; ci < 8; ci++) {
                const float* lp = tile + (ci * 18 + kd * 6 + wl0 + kw) * 64;
                float v0 = lp[hc0] * mh0;
                float v1 = lp[h];
                float v2 = lp[hc2] * mh2;
                const float* wp = wrow + ci * 18;
#pragma unroll
                for (int c = 0; c < 18; c++) {
                    float a = acc[c];
                    a = fmaf(v0, wp[c], a);
                    a = fmaf(v1, wp[144 + c], a);
                    a = fmaf(v2, wp[288 + c], a);
                    acc[c] = a;
                }
            }
        }
    }

#pragma unroll
    for (int c = 0; c < 18; c++) offs[c * VOX + idx] = acc[c];

    __shared__ float ls[36];
    if (tid < 36) ls[tid] = 0.f;
    __syncthreads();
#pragma unroll
    for (int c = 0; c < 18; c++) {
        float s = acc[c], q = acc[c] * acc[c];
#pragma unroll
        for (int o = 32; o > 0; o >>= 1) {
            s += __shfl_xor(s, o);
            q += __shfl_xor(q, o);
        }
        if ((tid & 63) == 0) {
            atomicAdd(&ls[c], s);
            atomicAdd(&ls[18 + c], q);
        }
    }
    __syncthreads();
    if (tid < 36) atomicAdd(&stats[tid], ls[tid]);
}

// ---- main: BN affine + fast_tanh + center-out cumsum + bilinear(z,y) gather +
//      (1,1,9) conv + GroupNorm stats. R11-proven body; ONLY delta: ft is fp16
//      (4 MB footprint -> one-XCD-L2 resident; 4 gather loads/tap instead of 8). ----
__global__ __launch_bounds__(256) void k_main(
        const __half* __restrict__ fth, const float* __restrict__ offs,
        const float* __restrict__ stats, const float* __restrict__ bn_g,
        const float* __restrict__ bn_b, const float* __restrict__ dw,
        const float* __restrict__ db, float* __restrict__ out,
        float* __restrict__ gstats) {
    int idx = blockIdx.x * 256 + threadIdx.x;
    int h = idx & 63, wy = (idx >> 6) & 63, d = idx >> 12;
    const float inv = 1.f / (float)VOX;

    float zo[9], yo[9];
#pragma unroll
    for (int c = 0; c < 18; c++) {
        float m = stats[c] * inv;
        float var = stats[18 + c] * inv - m * m;
        float rs = rsqrtf(var + 1e-5f);
        float t = fast_tanh(bn_g[c] * ((offs[c * VOX + idx] - m) * rs) + bn_b[c]);
        if (c < 9) zo[c] = t; else yo[c - 9] = t;
    }

    // cumsum outward from center (K=9, CENTER=4)
    float za[9], ya[9];
    za[4] = zo[4]; ya[4] = yo[4];
#pragma unroll
    for (int k = 5; k < 9; k++) { za[k] = za[k - 1] + zo[k]; ya[k] = ya[k - 1] + yo[k]; }
#pragma unroll
    for (int k = 3; k >= 0; k--) { za[k] = za[k + 1] + zo[k]; ya[k] = ya[k + 1] + yo[k]; }

    float acc[16];
#pragma unroll
    for (int co = 0; co < 16; co++) acc[co] = db[co];

#pragma unroll
    for (int k = 0; k < 9; k++) {
        int xi = h + k - 4;
        // x is exactly integer: weight 1 for xi in [0,62], exactly 0 otherwise
        // (incl. xi==63 where both clipped x-weights vanish).
        if (xi >= 0 && xi <= 62) {
            float z = (float)d + za[k];
            float y = (float)wy + ya[k];
            float fz = floorf(z), fy = floorf(y);
            int iz = (int)fz, iy = (int)fy;
            int z0 = clampi(iz, 0, 63), z1 = clampi(iz + 1, 0, 63);
            int y0 = clampi(iy, 0, 63), y1 = clampi(iy + 1, 0, 63);
            float wz0 = (float)z1 - z, wz1 = z - (float)z0;
            float wy0 = (float)y1 - y, wy1 = y - (float)y0;
            float w00 = wz0 * wy0, w01 = wz0 * wy1, w10 = wz1 * wy0, w11 = wz1 * wy1;

            // 4 gather loads of 16B (8 fp16 channels) each
            float4 r00 = *(const float4*)(fth + (((z0 * 64 + y0) * 64 + xi) << 3));
            float4 r01 = *(const float4*)(fth + (((z0 * 64 + y1) * 64 + xi) << 3));
            float4 r10 = *(const float4*)(fth + (((z1 * 64 + y0) * 64 + xi) << 3));
            float4 r11 = *(const float4*)(fth + (((z1 * 64 + y1) * 64 + xi) << 3));
            const __half2* h00 = (const __half2*)&r00;
            const __half2* h01 = (const __half2*)&r01;
            const __half2* h10 = (const __half2*)&r10;
            const __half2* h11 = (const __half2*)&r11;

            float v[8];
#pragma unroll
            for (int j = 0; j < 4; j++) {
                float2 a = __half22float2(h00[j]);
                float2 b = __half22float2(h01[j]);
                float2 c = __half22float2(h10[j]);
                float2 e = __half22float2(h11[j]);
                v[2 * j]     = w00 * a.x + w01 * b.x + w10 * c.x + w11 * e.x;
                v[2 * j + 1] = w00 * a.y + w01 * b.y + w10 * c.y + w11 * e.y;
            }

#pragma unroll
            for (int ci = 0; ci < 8; ci++) {
#pragma unroll
                for (int co = 0; co < 16; co++)
                    acc[co] = fmaf(v[ci], dw[(co * 8 + ci) * 9 + k], acc[co]);
            }
        }
    }

#pragma unroll
    for (int co = 0; co < 16; co++) out[co * VOX + idx] = acc[co];

    // group-norm stats: 4 groups of 4 channels
    __shared__ float ls[8];
    if (threadIdx.x < 8) ls[threadIdx.x] = 0.f;
    __syncthreads();
#pragma unroll
    for (int g = 0; g < 4; g++) {
        float s = acc[4 * g] + acc[4 * g + 1] + acc[4 * g + 2] + acc[4 * g + 3];
        float q = acc[4 * g] * acc[4 * g] + acc[4 * g + 1] * acc[4 * g + 1]
                + acc[4 * g + 2] * acc[4 * g + 2] + acc[4 * g + 3] * acc[4 * g + 3];
#pragma unroll
        for (int o = 32; o > 0; o >>= 1) {
            s += __shfl_xor(s, o);
            q += __shfl_xor(q, o);
        }
        if ((threadIdx.x & 63) == 0) {
            atomicAdd(&ls[g], s);
            atomicAdd(&ls[4 + g], q);
        }
    }
    __syncthreads();
    if (threadIdx.x < 8) atomicAdd(&gstats[threadIdx.x], ls[threadIdx.x]);
}

// ---- apply GroupNorm + ReLU in place on d_out (float4) ----
__global__ void k_gn(const float* __restrict__ gstats, const float* __restrict__ gn_g,
                     const float* __restrict__ gn_b, float* __restrict__ out) {
    int i = blockIdx.x * 256 + threadIdx.x;  // over 16*VOX/4 float4s
    int c = i >> 16;                         // (i*4)/VOX
    int g = c >> 2;
    const float invn = 1.f / (4.f * (float)VOX);
    float m = gstats[g] * invn;
    float var = gstats[4 + g] * invn - m * m;
    float rs = rsqrtf(var + 1e-5f);
    float gg = gn_g[c], gb = gn_b[c];
    float4 v = ((float4*)out)[i];
    v.x = (v.x - m) * rs * gg + gb; v.x = v.x > 0.f ? v.x : 0.f;
    v.y = (v.y - m) * rs * gg + gb; v.y = v.y > 0.f ? v.y : 0.f;
    v.z = (v.z - m) * rs * gg + gb; v.z = v.z > 0.f ? v.z : 0.f;
    v.w = (v.w - m) * rs * gg + gb; v.w = v.w > 0.f ? v.w : 0.f;
    ((float4*)out)[i] = v;
}

extern "C" void kernel_launch(void* const* d_in, const int* in_sizes, int n_in,
                              void* d_out, int out_size, void* d_ws, size_t ws_size,
                              hipStream_t stream) {
    const float* f    = (const float*)d_in[0];
    const float* offw = (const float*)d_in[1];
    const float* offb = (const float*)d_in[2];
    const float* bng  = (const float*)d_in[3];
    const float* bnb  = (const float*)d_in[4];
    const float* dcnw = (const float*)d_in[5];
    const float* dcnb = (const float*)d_in[6];
    const float* gng  = (const float*)d_in[7];
    const float* gnb  = (const float*)d_in[8];
    float* out = (float*)d_out;

    float* ws     = (float*)d_ws;
    __half* fth   = (__half*)ws;      // 8*VOX halves = 4*VOX floats (fp16 featT)
    float* offs   = ws + 4 * VOX;     // 18*VOX floats (raw offset conv)
    float* stats  = offs + 18 * VOX;  // 36 bn stats + 8 gn stats
    float* gstats = stats + 36;
    // wT lives in d_out's first 3888 floats: dead until k_main overwrites out.
    float* wT = out;

    hipLaunchKernelGGL(k_pre, dim3(VOX / 256), dim3(256), 0, stream, f, fth, offw, wT, stats);
    hipLaunchKernelGGL(k_conv_off, dim3(VOX / 256), dim3(256), 0, stream,
                       f, wT, offb, offs, stats);
    hipLaunchKernelGGL(k_main, dim3(VOX / 256), dim3(256), 0, stream,
                       fth, offs, stats, bng, bnb, dcnw, dcnb, out, gstats);
    hipLaunchKernelGGL(k_gn, dim3((16 * VOX / 4) / 256), dim3(256), 0, stream,
                       gstats, gng, gnb, out);
}